// Round 3
// baseline (173.073 us; speedup 1.0000x reference)
//
#include <hip/hip_runtime.h>
#include <hip/hip_bf16.h>

typedef __bf16 bf16;
typedef __bf16 bf16x4 __attribute__((ext_vector_type(4)));
typedef __bf16 bf16x8 __attribute__((ext_vector_type(8)));
typedef float f32x4 __attribute__((ext_vector_type(4)));

#define MFMA16(a, b, c) __builtin_amdgcn_mfma_f32_16x16x32_bf16((a), (b), (c), 0, 0, 0)

// async global->LDS, 16B per lane; LDS dest = wave-uniform base + lane*16.
__device__ __forceinline__ void async16(const void* g, void* l) {
  typedef const unsigned int __attribute__((address_space(1))) * GP;
  typedef unsigned int __attribute__((address_space(3))) * LP;
  __builtin_amdgcn_global_load_lds((GP)g, (LP)l, 16, 0, 0);
}

// ---------------------------------------------------------------------------
// prep: z<4 -> transpose+convert weight z (fp32 [1024x1024] -> bf16 Wt[n][k]);
// z==4 -> convert x fp32 -> bf16. grid (16,16,5) x 256 threads.
// ---------------------------------------------------------------------------
__global__ __launch_bounds__(256) void prep(
    const float* __restrict__ w0, const float* __restrict__ w1,
    const float* __restrict__ w2, const float* __restrict__ w3,
    const float* __restrict__ x, bf16* __restrict__ wtOut,
    bf16* __restrict__ xOut) {
  const int t = threadIdx.x;
  if (blockIdx.z == 4) {  // x conversion
    size_t base = ((size_t)(blockIdx.y * 16 + blockIdx.x)) * 16384;
#pragma unroll
    for (int p = 0; p < 16; ++p) {
      size_t i = base + (size_t)(p * 256 + t) * 4;
      f32x4 v = *(const f32x4*)&x[i];
      bf16 o[4];
#pragma unroll
      for (int j = 0; j < 4; ++j) o[j] = (bf16)v[j];
      *(ulong1*)&xOut[i] = *(ulong1*)o;
    }
    return;
  }
  __shared__ __align__(16) float tile[64][68];
  const float* src = (blockIdx.z == 0) ? w0 : (blockIdx.z == 1) ? w1
                   : (blockIdx.z == 2) ? w2 : w3;
  bf16* dst = wtOut + (size_t)blockIdx.z * (1024u * 1024u);
  const int bx = blockIdx.x, by = blockIdx.y;
#pragma unroll
  for (int p = 0; p < 4; ++p) {
    int idx = t + p * 256;
    int r = idx >> 4, c4 = idx & 15;
    *(f32x4*)&tile[r][c4 * 4] =
        *(const f32x4*)&src[(size_t)(by * 64 + r) * 1024 + bx * 64 + c4 * 4];
  }
  __syncthreads();
#pragma unroll
  for (int p = 0; p < 2; ++p) {
    int idx = t + p * 256;
    int rn = idx >> 3, c8 = idx & 7;
    bf16x8 v;
#pragma unroll
    for (int i = 0; i < 8; ++i) v[i] = (bf16)tile[c8 * 8 + i][rn];
    *(bf16x8*)&dst[(size_t)(bx * 64 + rn) * 1024 + by * 64 + c8 * 8] = v;
  }
}

// ---------------------------------------------------------------------------
// QKV GEMM v2 (round-3): 256x256 tile, BK=64, counted-vmcnt multi-phase
// (T2+T3+T4+T5 stack per the catalog; 128^2/2-phase techniques are measured
// NULL). 512 thr = 8 waves (2M x 4N), per-wave 128x64 out (8x4 frags).
// LDS 128 KB (2 dbuf x (A 32KB + B 32KB)), 1 blk/CU. Per K-tile: 4 MFMA
// clusters of 16 (setprio-wrapped), then: s_barrier (reads done block-wide)
// -> STAGE tile kt+2 into the buffer just read -> s_waitcnt vmcnt(8) (waits
// tile kt+1 landed; kt+2's 8 loads stay IN FLIGHT across the barrier —
// never vmcnt(0) in steady state) -> s_barrier.
// Both-sides LDS swizzle (128-B rows, same proven pattern as attn):
// stage source k-slot = (lane&7)^(lane>>3); read slot = kslot^(l16&7).
// z grid.y: z=0 scaled by scaleZ0 (Q), z=1 K, z=2 fused pi-permuted V^T
// epilogue (wave's 64-col strip = exactly one head).
// ---------------------------------------------------------------------------
__global__ __launch_bounds__(512, 2) void qkv256(
    const bf16* __restrict__ A, const bf16* __restrict__ Bt,
    bf16* __restrict__ C, int btStrideZ, int cStrideZ, float scaleZ0,
    bf16* __restrict__ vtOut) {
  const int bid = blockIdx.x;             // 0..63 per z
  const int rr = bid & 7, tt = bid >> 3;  // XCD-aware swizzle (64%8==0)
  const int xb = tt & 3, yb = (tt >> 2) * 8 + rr;
  const int zi = blockIdx.y;

  const int tid = threadIdx.x;
  const int wave = tid >> 6, lane = tid & 63;
  const int quad = lane >> 4, l16 = lane & 15;
  const int wm = wave >> 2, wn = wave & 3;
  const int m0 = yb * 256, n0 = xb * 256;
  const bf16* Bz = Bt + (size_t)zi * (size_t)btStrideZ;
  bf16* Cz = C + (size_t)zi * (size_t)cStrideZ;
  const float sc = (zi == 0) ? scaleZ0 : 1.0f;

  __shared__ __align__(16) bf16 lsA[2][256 * 64];  // 64 KB
  __shared__ __align__(16) bf16 lsB[2][256 * 64];  // 64 KB

  const int lrow = lane >> 3;           // row within 8-row chunk (= row&7)
  const int cgX = (lane & 7) ^ lrow;    // pre-swizzled global k-slot

  f32x4 acc[8][4];
#pragma unroll
  for (int i = 0; i < 8; ++i)
#pragma unroll
    for (int j = 0; j < 4; ++j) acc[i][j] = (f32x4){0.f, 0.f, 0.f, 0.f};

#define QKV_STAGE(buf, kt)                                                   \
  {                                                                          \
    const int k0_ = (kt)*64;                                                 \
    _Pragma("unroll") for (int c = 0; c < 4; ++c) {                          \
      int chunk = wave * 4 + c;                                              \
      int row = chunk * 8 + lrow;                                            \
      async16(&A[(size_t)(m0 + row) * 1024 + k0_ + cgX * 8],                 \
              &lsA[buf][chunk * 512]);                                       \
    }                                                                        \
    _Pragma("unroll") for (int c = 0; c < 4; ++c) {                          \
      int chunk = wave * 4 + c;                                              \
      int row = chunk * 8 + lrow;                                            \
      async16(&Bz[(size_t)(n0 + row) * 1024 + k0_ + cgX * 8],                \
              &lsB[buf][chunk * 512]);                                       \
    }                                                                        \
  }

  QKV_STAGE(0, 0);
  QKV_STAGE(1, 1);
  asm volatile("s_waitcnt vmcnt(8)" ::: "memory");  // tile0 landed (mine)
  __builtin_amdgcn_s_barrier();                     // tile0 landed (all)

  for (int kt = 0; kt < 16; ++kt) {
    const int cur = kt & 1;
#pragma unroll
    for (int ks = 0; ks < 2; ++ks) {
      bf16x8 bfr[4];
#pragma unroll
      for (int ni = 0; ni < 4; ++ni) {
        int rb = wn * 64 + ni * 16 + l16;
        bfr[ni] = *(const bf16x8*)&lsB[cur][rb * 64 +
                                            (((ks * 4 + quad) ^ (l16 & 7)) *
                                             8)];
      }
#pragma unroll
      for (int mh = 0; mh < 2; ++mh) {
        bf16x8 af[4];
#pragma unroll
        for (int i = 0; i < 4; ++i) {
          int ra = wm * 128 + (mh * 4 + i) * 16 + l16;
          af[i] = *(const bf16x8*)&lsA[cur][ra * 64 +
                                            (((ks * 4 + quad) ^ (l16 & 7)) *
                                             8)];
        }
        __builtin_amdgcn_s_setprio(1);
#pragma unroll
        for (int i = 0; i < 4; ++i)
#pragma unroll
          for (int ni = 0; ni < 4; ++ni)
            acc[mh * 4 + i][ni] = MFMA16(af[i], bfr[ni], acc[mh * 4 + i][ni]);
        __builtin_amdgcn_s_setprio(0);
      }
    }
    // All reads of buf[cur] complete (consumed by MFMAs above) block-wide:
    __builtin_amdgcn_s_barrier();
    if (kt + 2 < 16) {
      QKV_STAGE(cur, kt + 2);  // overwrite the buffer we just finished reading
      asm volatile("s_waitcnt vmcnt(8)" ::: "memory");  // tile kt+1 landed
    } else {
      asm volatile("s_waitcnt vmcnt(0)" ::: "memory");  // drain tail
    }
    __builtin_amdgcn_s_barrier();  // tile kt+1 visible to all waves
  }
#undef QKV_STAGE

  if (zi == 2 && vtOut != nullptr) {
    // V: transposed per head -> vt[(b*16+h)][d][sPerm], pi-permuted keys.
#pragma unroll
    for (int mi = 0; mi < 8; ++mi)
#pragma unroll
      for (int ni = 0; ni < 4; ++ni) {
        int col = n0 + wn * 64 + ni * 16 + l16;
        int hd = col >> 6, d = col & 63;
        int row = m0 + wm * 128 + mi * 16 + quad * 4;
        int b = row >> 11, s = row & 2047;
        int s32 = s & 31;
        int sp = (s & ~31) + ((s32 & 12) << 1) + ((s32 >> 4) << 2);
        bf16 o[4];
#pragma unroll
        for (int r = 0; r < 4; ++r) o[r] = (bf16)acc[mi][ni][r];
        *(ulong1*)&vtOut[((size_t)(b * 16 + hd) * 64 + d) * 2048 + sp] =
            *(ulong1*)o;
      }
  } else {
#pragma unroll
    for (int mi = 0; mi < 8; ++mi)
#pragma unroll
      for (int ni = 0; ni < 4; ++ni) {
        int col = n0 + wn * 64 + ni * 16 + l16;
#pragma unroll
        for (int r = 0; r < 4; ++r) {
          int row = m0 + wm * 128 + mi * 16 + quad * 4 + r;
          Cz[(size_t)row * 1024 + col] = (bf16)(acc[mi][ni][r] * sc);
        }
      }
  }
}

// ---------------------------------------------------------------------------
// GEMM (round-13): C = A @ W (Bt[n][k]). 128 x (NI*32) tile, BK=32 dbuf
// global_load_lds, one barrier per K-step. Retained for the output
// projection (proj at 256^2 would be 64 blocks = 0.25/CU — worse).
// ---------------------------------------------------------------------------
template <typename OutT, int NI>
__global__ __launch_bounds__(256, 4) void gemm_bt(
    const bf16* __restrict__ A, const bf16* __restrict__ Bt,
    OutT* __restrict__ C, int btStrideZ, int cStrideZ, float scaleZ0,
    bf16* __restrict__ vtOut) {
  constexpr int XT = 1024 / (NI * 32);
  const int bid = blockIdx.x;
  const int rr = bid & 7, tt = bid >> 3;
  const int xb = tt % XT, yb = (tt / XT) * 8 + rr;
  const int zi = blockIdx.y;

  const int tid = threadIdx.x;
  const int wave = tid >> 6, lane = tid & 63;
  const int quad = lane >> 4, l16 = lane & 15;
  const int wm = wave >> 1, wn = wave & 1;
  const int m0 = yb * 128, n0 = xb * (NI * 32);
  const bf16* Bz = Bt + (size_t)zi * (size_t)btStrideZ;
  OutT* Cz = C + (size_t)zi * (size_t)cStrideZ;
  const float sc = (zi == 0) ? scaleZ0 : 1.0f;

  __shared__ __align__(16) bf16 lsA[2][128 * 32];
  __shared__ __align__(16) bf16 lsB[2][NI * 32 * 32];

  const int lrow = lane >> 2;
  const int cgX = (lane & 3) ^ ((lrow >> 1) & 3);
  const int fR = (l16 >> 1) & 3;

  f32x4 acc[4][NI];
#pragma unroll
  for (int i = 0; i < 4; ++i)
#pragma unroll
    for (int j = 0; j < NI; ++j) acc[i][j] = (f32x4){0.f, 0.f, 0.f, 0.f};

#pragma unroll
  for (int c = 0; c < 2; ++c) {
    int chunk = wave * 2 + c;
    int row = chunk * 16 + lrow;
    async16(&A[(size_t)(m0 + row) * 1024 + cgX * 8], &lsA[0][chunk * 512]);
  }
#pragma unroll
  for (int c = 0; c < NI / 2; ++c) {
    int chunk = wave * (NI / 2) + c;
    int row = chunk * 16 + lrow;
    async16(&Bz[(size_t)(n0 + row) * 1024 + cgX * 8], &lsB[0][chunk * 512]);
  }
  __syncthreads();

  for (int it = 0; it < 32; ++it) {
    const int cur = it & 1;
    if (it < 31) {
      int k0n = (it + 1) * 32;
#pragma unroll
      for (int c = 0; c < 2; ++c) {
        int chunk = wave * 2 + c;
        int row = chunk * 16 + lrow;
        async16(&A[(size_t)(m0 + row) * 1024 + k0n + cgX * 8],
                &lsA[cur ^ 1][chunk * 512]);
      }
#pragma unroll
      for (int c = 0; c < NI / 2; ++c) {
        int chunk = wave * (NI / 2) + c;
        int row = chunk * 16 + lrow;
        async16(&Bz[(size_t)(n0 + row) * 1024 + k0n + cgX * 8],
                &lsB[cur ^ 1][chunk * 512]);
      }
    }

    bf16x8 af[4], bfr[NI];
#pragma unroll
    for (int i = 0; i < 4; ++i) {
      int ra = wm * 64 + i * 16 + l16;
      af[i] = *(const bf16x8*)&lsA[cur][ra * 32 + ((quad ^ fR) * 8)];
    }
#pragma unroll
    for (int ni = 0; ni < NI; ++ni) {
      int rb = wn * (NI * 16) + ni * 16 + l16;
      bfr[ni] = *(const bf16x8*)&lsB[cur][rb * 32 + ((quad ^ fR) * 8)];
    }
#pragma unroll
    for (int mi = 0; mi < 4; ++mi)
#pragma unroll
      for (int ni = 0; ni < NI; ++ni)
        acc[mi][ni] = MFMA16(af[mi], bfr[ni], acc[mi][ni]);

    __syncthreads();
  }

  if (zi == 2 && vtOut != nullptr) {
#pragma unroll
    for (int mi = 0; mi < 4; ++mi)
#pragma unroll
      for (int ni = 0; ni < NI; ++ni) {
        int col = n0 + wn * (NI * 16) + ni * 16 + l16;
        int hd = col >> 6, d = col & 63;
        int row = m0 + wm * 64 + mi * 16 + quad * 4;
        int b = row >> 11, s = row & 2047;
        int s32 = s & 31;
        int sp = (s & ~31) + ((s32 & 12) << 1) + ((s32 >> 4) << 2);
        bf16 o[4];
#pragma unroll
        for (int r = 0; r < 4; ++r) o[r] = (bf16)acc[mi][ni][r];
        *(ulong1*)&vtOut[((size_t)(b * 16 + hd) * 64 + d) * 2048 + sp] =
            *(ulong1*)o;
      }
  } else {
#pragma unroll
    for (int mi = 0; mi < 4; ++mi)
#pragma unroll
      for (int ni = 0; ni < NI; ++ni) {
        int col = n0 + wn * (NI * 16) + ni * 16 + l16;
#pragma unroll
        for (int r = 0; r < 4; ++r) {
          int row = m0 + wm * 64 + mi * 16 + quad * 4 + r;
          Cz[(size_t)row * 1024 + col] = (OutT)(acc[mi][ni][r] * sc);
        }
      }
  }
}

// ---------------------------------------------------------------------------
// Flash attention v8.1 (round-2, neutral vs v7 — kept): amortized wave
// mapping (4 q-groups x 2 tile parities), key-half-split register lifetimes,
// 4-slot LDS rotation, one barrier per tile pair, cross-parity LDS combine.
// ---------------------------------------------------------------------------
__global__ __launch_bounds__(512, 4) void attn_fwd(
    const bf16* __restrict__ Q, const bf16* __restrict__ K,
    const bf16* __restrict__ Vt, bf16* __restrict__ O) {
  const int bid = blockIdx.x;
  const int x = bid & 15, hb = bid >> 4;
  const int h = hb & 15, b = hb >> 4;
  const int qt = b ? (15 - x) : x;
  const int tid = threadIdx.x;
  const int wave = tid >> 6, lane = tid & 63;
  const int quad = lane >> 4, l16 = lane & 15;
  const int wq = wave >> 1;  // q-group: rows wq*32 .. wq*32+31
  const int par = wave & 1;  // tile parity: kt == par (mod 2)

  __shared__ __align__(16) bf16 SMEM[32768];  // 64 KB, 4 slots x 8192
  bf16* Qs = &SMEM[16384];  // Q overlays slot 2

  const size_t base = ((size_t)b * 2048) * 1024 + (size_t)h * 64;
  const bf16* Qb = Q + base;
  const bf16* Kb = K + base;
  const bf16* Vtb = Vt + ((size_t)(b * 16 + h)) * 64 * 2048;
  bf16* Ob = O + base;

  const int lrow = lane >> 3;
  const int cgX = (lane & 7) ^ lrow;

#pragma unroll
  for (int c = 0; c < 2; ++c) {
    int chunk = wave * 2 + c;
    int row = chunk * 8 + lrow;
    async16(&Qb[(size_t)(qt * 128 + row) * 1024 + cgX * 8], &Qs[chunk * 512]);
  }
  {
    int row = wave * 8 + lrow;
    async16(&Kb[(size_t)row * 1024 + cgX * 8], &SMEM[0 * 8192 + wave * 512]);
    async16(&Vtb[(size_t)row * 2048 + cgX * 8],
            &SMEM[0 * 8192 + 4096 + wave * 512]);
    async16(&Kb[(size_t)(64 + row) * 1024 + cgX * 8],
            &SMEM[1 * 8192 + wave * 512]);
    async16(&Vtb[(size_t)row * 2048 + 64 + cgX * 8],
            &SMEM[1 * 8192 + 4096 + wave * 512]);
  }
  __syncthreads();

  bf16x8 aq[2][2];  // [q-subgroup g][k-chunk]
#pragma unroll
  for (int g = 0; g < 2; ++g)
#pragma unroll
    for (int ks = 0; ks < 2; ++ks) {
      int row = wq * 32 + g * 16 + l16;
      aq[g][ks] =
          *(const bf16x8*)&Qs[row * 64 + (((ks * 4 + quad) ^ (l16 & 7)) * 8)];
    }
  __syncthreads();  // Q-frag reads done before slot 2 is overwritten

  const float NEG_INF = -__builtin_inff();
  f32x4 lsv[2];
  f32x4 Oacc[2][4];
#pragma unroll
  for (int g = 0; g < 2; ++g) {
    lsv[g] = (f32x4){0.f, 0.f, 0.f, 0.f};
#pragma unroll
    for (int nt = 0; nt < 4; ++nt) Oacc[g][nt] = (f32x4){0.f, 0.f, 0.f, 0.f};
  }

  const int two_qt = 2 * qt;
  const int kt_end = 2 * qt + 1;  // tile count 2qt+2 (even)

  for (int ktp = 0; ktp <= two_qt; ktp += 2) {
    {
      int row = wave * 8 + lrow;
      if (ktp + 2 <= kt_end) {
        int s2 = (ktp + 2) & 3;
        async16(&Kb[(size_t)((ktp + 2) * 64 + row) * 1024 + cgX * 8],
                &SMEM[s2 * 8192 + wave * 512]);
        async16(&Vtb[(size_t)row * 2048 + (ktp + 2) * 64 + cgX * 8],
                &SMEM[s2 * 8192 + 4096 + wave * 512]);
      }
      if (ktp + 3 <= kt_end) {
        int s3 = (ktp + 3) & 3;
        async16(&Kb[(size_t)((ktp + 3) * 64 + row) * 1024 + cgX * 8],
                &SMEM[s3 * 8192 + wave * 512]);
        async16(&Vtb[(size_t)row * 2048 + (ktp + 3) * 64 + cgX * 8],
                &SMEM[s3 * 8192 + 4096 + wave * 512]);
      }
    }

    const int kt = ktp + par;
    const int ko = (kt & 3) * 8192;
    const int vo = ko + 4096;
    const bool diag = (ktp == two_qt);
    const bool active = !diag || (par == 0) || (wq >= 2);

    if (active) {
#pragma unroll
      for (int a = 0; a < 2; ++a) {  // key-half: keys [a*32, a*32+32)
        f32x4 s[2][2];               // [g][t], t = 16-key block within half
#pragma unroll
        for (int t = 0; t < 2; ++t) {
          const int nt = 2 * a + t;
          const int row = nt * 16 + l16;
          bf16x8 bk0 =
              *(const bf16x8*)&SMEM[ko + row * 64 + ((quad ^ (l16 & 7)) * 8)];
          bf16x8 bk1 = *(const bf16x8*)&SMEM[ko + row * 64 +
                                             (((4 + quad) ^ (l16 & 7)) * 8)];
#pragma unroll
          for (int g = 0; g < 2; ++g) {
            f32x4 sv = (f32x4){0.f, 0.f, 0.f, 0.f};
            sv = MFMA16(bk0, aq[g][0], sv);
            sv = MFMA16(bk1, aq[g][1], sv);
            s[g][t] = sv;
          }
        }

        if (diag) {
#pragma unroll
          for (int g = 0; g < 2; ++g) {
            const int q_rel = wq * 32 + g * 16 + l16;
#pragma unroll
            for (int t = 0; t < 2; ++t) {
              const int kb = par * 64 + (2 * a + t) * 16 + quad * 4;
#pragma unroll
              for (int r = 0; r < 4; ++r)
                if (kb + r > q_rel) s[g][t][r] = NEG_INF;
            }
          }
        }

        bf16x8 apf[2];  // per-g P fragment for this key-half
#pragma unroll
        for (int g = 0; g < 2; ++g) {
#pragma unroll
          for (int t = 0; t < 2; ++t) {
#pragma unroll
            for (int r = 0; r < 4; ++r) s[g][t][r] = exp2f(s[g][t][r]);
            lsv[g] += s[g][t];
          }
          bf16x4 c0 = __builtin_convertvector(s[g][0], bf16x4);
          bf16x4 c1 = __builtin_convertvector(s[g][1], bf16x4);
#pragma unroll
          for (int i = 0; i < 4; ++i) {
            apf[g][i] = c0[i];
            apf[g][4 + i] = c1[i];
          }
        }

#pragma unroll
        for (int nt = 0; nt < 4; ++nt) {
          const int R = nt * 16 + l16;
          bf16x8 bvf = *(const bf16x8*)&SMEM[vo + R * 64 +
                                             (((a * 4 + quad) ^ (l16 & 7)) *
                                              8)];
#pragma unroll
          for (int g = 0; g < 2; ++g)
            Oacc[g][nt] = MFMA16(apf[g], bvf, Oacc[g][nt]);
        }
      }
    }

    __syncthreads();
  }

  // Per-wave quad reduction of the softmax denominator.
  float ls[2];
#pragma unroll
  for (int g = 0; g < 2; ++g) {
    float a_ = lsv[g][0] + lsv[g][1] + lsv[g][2] + lsv[g][3];
    a_ += __shfl_xor(a_, 16, 64);
    a_ += __shfl_xor(a_, 32, 64);
    ls[g] = a_;  // q = wq*32 + g*16 + l16 (replicated across quads)
  }

  // Cross-parity combine: par1 -> LDS, par0 adds + normalizes + stores.
  float* F = (float*)SMEM;
  const int roff = wq * 2176;  // 2048 O floats + 128 ls floats per q-group
  if (par == 1) {
#pragma unroll
    for (int g = 0; g < 2; ++g) {
#pragma unroll
      for (int nt = 0; nt < 4; ++nt)
        *(f32x4*)&F[roff + (g * 4 + nt) * 256 + lane * 4] = Oacc[g][nt];
      F[roff + 2048 + g * 64 + lane] = ls[g];
    }
  }
  __syncthreads();
  if (par == 0) {
#pragma unroll
    for (int g = 0; g < 2; ++g) {
#pragma unroll
      for (int nt = 0; nt < 4; ++nt)
        Oacc[g][nt] += *(const f32x4*)&F[roff + (g * 4 + nt) * 256 + lane * 4];
      ls[g] += F[roff + 2048 + g * 64 + lane];
    }
    float rl[2][4];
#pragma unroll
    for (int g = 0; g < 2; ++g)
#pragma unroll
      for (int r = 0; r < 4; ++r)
        rl[g][r] = 1.f / __shfl(ls[g], quad * 4 + r, 64);
#pragma unroll
    for (int g = 0; g < 2; ++g)
#pragma unroll
      for (int nt = 0; nt < 4; ++nt)
#pragma unroll
        for (int r = 0; r < 4; ++r) {
          int row = qt * 128 + wq * 32 + g * 16 + quad * 4 + r;
          Ob[(size_t)row * 1024 + nt * 16 + l16] =
              (bf16)(Oacc[g][nt][r] * rl[g][r]);
        }
  }
}

// ---------------------------------------------------------------------------
// Launch
// ---------------------------------------------------------------------------
extern "C" void kernel_launch(void* const* d_in, const int* in_sizes, int n_in,
                              void* d_out, int out_size, void* d_ws,
                              size_t ws_size, hipStream_t stream) {
  (void)in_sizes; (void)n_in; (void)out_size; (void)ws_size;
  const float* x  = (const float*)d_in[0];
  const float* Wq = (const float*)d_in[1];
  const float* Wk = (const float*)d_in[2];
  const float* Wv = (const float*)d_in[3];
  const float* Wo = (const float*)d_in[4];
  float* out = (float*)d_out;

  bf16* ws = (bf16*)d_ws;
  const size_t WELEM = 1024u * 1024u;
  const size_t TELEM = 4096u * 1024u;
  bf16* wt  = ws;               // 4 transposed weights (8 MB)
  bf16* xbf = ws + 4 * WELEM;   // x bf16 (8 MB)
  bf16* q   = xbf + TELEM;      // q (z=0), k (z=1) via cStrideZ
  bf16* k   = q + TELEM;
  bf16* vt  = k + TELEM;        // V pre-transposed + pi-permuted by QKV
  bf16* ao  = vt + TELEM;

  const float QSCALE = 0.125f * 1.44269504088896340736f;  // 1/sqrt(64)*log2e

  prep<<<dim3(16, 16, 5), 256, 0, stream>>>(Wq, Wk, Wv, Wo, x, wt, xbf);
  qkv256<<<dim3(64, 3), 512, 0, stream>>>(
      xbf, wt, q, (int)WELEM, (int)TELEM, QSCALE, vt);
  attn_fwd<<<dim3(512), 512, 0, stream>>>(q, k, vt, ao);
  gemm_bt<float, 2><<<dim3(512, 1), 256, 0, stream>>>(
      ao, wt + 3 * WELEM, out, 0, 0, 1.0f, nullptr);
}

// Round 4
// 169.118 us; speedup vs baseline: 1.0234x; 1.0234x over previous
//
#include <hip/hip_runtime.h>
#include <hip/hip_bf16.h>

typedef __bf16 bf16;
typedef __bf16 bf16x4 __attribute__((ext_vector_type(4)));
typedef __bf16 bf16x8 __attribute__((ext_vector_type(8)));
typedef float f32x4 __attribute__((ext_vector_type(4)));

#define MFMA16(a, b, c) __builtin_amdgcn_mfma_f32_16x16x32_bf16((a), (b), (c), 0, 0, 0)

// async global->LDS, 16B per lane; LDS dest = wave-uniform base + lane*16.
__device__ __forceinline__ void async16(const void* g, void* l) {
  typedef const unsigned int __attribute__((address_space(1))) * GP;
  typedef unsigned int __attribute__((address_space(3))) * LP;
  __builtin_amdgcn_global_load_lds((GP)g, (LP)l, 16, 0, 0);
}

// ---------------------------------------------------------------------------
// prep: z<4 -> transpose+convert weight z (fp32 [1024x1024] -> bf16 Wt[n][k]);
// z==4 -> convert x fp32 -> bf16. grid (16,16,5) x 256 threads.
// ---------------------------------------------------------------------------
__global__ __launch_bounds__(256) void prep(
    const float* __restrict__ w0, const float* __restrict__ w1,
    const float* __restrict__ w2, const float* __restrict__ w3,
    const float* __restrict__ x, bf16* __restrict__ wtOut,
    bf16* __restrict__ xOut) {
  const int t = threadIdx.x;
  if (blockIdx.z == 4) {  // x conversion
    size_t base = ((size_t)(blockIdx.y * 16 + blockIdx.x)) * 16384;
#pragma unroll
    for (int p = 0; p < 16; ++p) {
      size_t i = base + (size_t)(p * 256 + t) * 4;
      f32x4 v = *(const f32x4*)&x[i];
      bf16 o[4];
#pragma unroll
      for (int j = 0; j < 4; ++j) o[j] = (bf16)v[j];
      *(ulong1*)&xOut[i] = *(ulong1*)o;
    }
    return;
  }
  __shared__ __align__(16) float tile[64][68];
  const float* src = (blockIdx.z == 0) ? w0 : (blockIdx.z == 1) ? w1
                   : (blockIdx.z == 2) ? w2 : w3;
  bf16* dst = wtOut + (size_t)blockIdx.z * (1024u * 1024u);
  const int bx = blockIdx.x, by = blockIdx.y;
#pragma unroll
  for (int p = 0; p < 4; ++p) {
    int idx = t + p * 256;
    int r = idx >> 4, c4 = idx & 15;
    *(f32x4*)&tile[r][c4 * 4] =
        *(const f32x4*)&src[(size_t)(by * 64 + r) * 1024 + bx * 64 + c4 * 4];
  }
  __syncthreads();
#pragma unroll
  for (int p = 0; p < 2; ++p) {
    int idx = t + p * 256;
    int rn = idx >> 3, c8 = idx & 7;
    bf16x8 v;
#pragma unroll
    for (int i = 0; i < 8; ++i) v[i] = (bf16)tile[c8 * 8 + i][rn];
    *(bf16x8*)&dst[(size_t)(bx * 64 + rn) * 1024 + by * 64 + c8 * 8] = v;
  }
}

// ---------------------------------------------------------------------------
// GEMM (round-13 config, reverted after R3's 256^2 regression: 192 blocks
// < 256 CUs -> 75% chip util lost more than the 8-phase schedule gained).
// C = A @ W (Bt[n][k]). 128 x (NI*32) tile, BK=32 dbuf global_load_lds,
// one barrier per K-step. XCD-swizzled 1D grid. z==0 scaled by scaleZ0;
// z==2 with vtOut: fused V^T epilogue with the PI-PERMUTED key layout.
// QKV: NI=4 (grid 256/z, 4 blk/CU via z-interleave). proj: NI=2 (grid 512).
// ---------------------------------------------------------------------------
template <typename OutT, int NI>
__global__ __launch_bounds__(256, 4) void gemm_bt(
    const bf16* __restrict__ A, const bf16* __restrict__ Bt,
    OutT* __restrict__ C, int btStrideZ, int cStrideZ, float scaleZ0,
    bf16* __restrict__ vtOut) {
  constexpr int XT = 1024 / (NI * 32);
  const int bid = blockIdx.x;
  const int rr = bid & 7, tt = bid >> 3;
  const int xb = tt % XT, yb = (tt / XT) * 8 + rr;
  const int zi = blockIdx.y;

  const int tid = threadIdx.x;
  const int wave = tid >> 6, lane = tid & 63;
  const int quad = lane >> 4, l16 = lane & 15;
  const int wm = wave >> 1, wn = wave & 1;
  const int m0 = yb * 128, n0 = xb * (NI * 32);
  const bf16* Bz = Bt + (size_t)zi * (size_t)btStrideZ;
  OutT* Cz = C + (size_t)zi * (size_t)cStrideZ;
  const float sc = (zi == 0) ? scaleZ0 : 1.0f;

  __shared__ __align__(16) bf16 lsA[2][128 * 32];
  __shared__ __align__(16) bf16 lsB[2][NI * 32 * 32];

  const int lrow = lane >> 2;
  const int cgX = (lane & 3) ^ ((lrow >> 1) & 3);
  const int fR = (l16 >> 1) & 3;

  f32x4 acc[4][NI];
#pragma unroll
  for (int i = 0; i < 4; ++i)
#pragma unroll
    for (int j = 0; j < NI; ++j) acc[i][j] = (f32x4){0.f, 0.f, 0.f, 0.f};

#pragma unroll
  for (int c = 0; c < 2; ++c) {
    int chunk = wave * 2 + c;
    int row = chunk * 16 + lrow;
    async16(&A[(size_t)(m0 + row) * 1024 + cgX * 8], &lsA[0][chunk * 512]);
  }
#pragma unroll
  for (int c = 0; c < NI / 2; ++c) {
    int chunk = wave * (NI / 2) + c;
    int row = chunk * 16 + lrow;
    async16(&Bz[(size_t)(n0 + row) * 1024 + cgX * 8], &lsB[0][chunk * 512]);
  }
  __syncthreads();

  for (int it = 0; it < 32; ++it) {
    const int cur = it & 1;
    if (it < 31) {
      int k0n = (it + 1) * 32;
#pragma unroll
      for (int c = 0; c < 2; ++c) {
        int chunk = wave * 2 + c;
        int row = chunk * 16 + lrow;
        async16(&A[(size_t)(m0 + row) * 1024 + k0n + cgX * 8],
                &lsA[cur ^ 1][chunk * 512]);
      }
#pragma unroll
      for (int c = 0; c < NI / 2; ++c) {
        int chunk = wave * (NI / 2) + c;
        int row = chunk * 16 + lrow;
        async16(&Bz[(size_t)(n0 + row) * 1024 + k0n + cgX * 8],
                &lsB[cur ^ 1][chunk * 512]);
      }
    }

    bf16x8 af[4], bfr[NI];
#pragma unroll
    for (int i = 0; i < 4; ++i) {
      int ra = wm * 64 + i * 16 + l16;
      af[i] = *(const bf16x8*)&lsA[cur][ra * 32 + ((quad ^ fR) * 8)];
    }
#pragma unroll
    for (int ni = 0; ni < NI; ++ni) {
      int rb = wn * (NI * 16) + ni * 16 + l16;
      bfr[ni] = *(const bf16x8*)&lsB[cur][rb * 32 + ((quad ^ fR) * 8)];
    }
#pragma unroll
    for (int mi = 0; mi < 4; ++mi)
#pragma unroll
      for (int ni = 0; ni < NI; ++ni)
        acc[mi][ni] = MFMA16(af[mi], bfr[ni], acc[mi][ni]);

    __syncthreads();
  }

  if (zi == 2 && vtOut != nullptr) {
    // V: transposed per head -> vt[(b*16+h)][d][sPerm], pi-permuted keys.
#pragma unroll
    for (int mi = 0; mi < 4; ++mi)
#pragma unroll
      for (int ni = 0; ni < NI; ++ni) {
        int col = n0 + wn * (NI * 16) + ni * 16 + l16;
        int hd = col >> 6, d = col & 63;
        int row = m0 + wm * 64 + mi * 16 + quad * 4;
        int b = row >> 11, s = row & 2047;
        int s32 = s & 31;
        int sp = (s & ~31) + ((s32 & 12) << 1) + ((s32 >> 4) << 2);
        bf16 o[4];
#pragma unroll
        for (int r = 0; r < 4; ++r) o[r] = (bf16)acc[mi][ni][r];
        *(ulong1*)&vtOut[((size_t)(b * 16 + hd) * 64 + d) * 2048 + sp] =
            *(ulong1*)o;
      }
  } else {
#pragma unroll
    for (int mi = 0; mi < 4; ++mi)
#pragma unroll
      for (int ni = 0; ni < NI; ++ni) {
        int col = n0 + wn * (NI * 16) + ni * 16 + l16;
#pragma unroll
        for (int r = 0; r < 4; ++r) {
          int row = m0 + wm * 64 + mi * 16 + quad * 4 + r;
          Cz[(size_t)row * 1024 + col] = (OutT)(acc[mi][ni][r] * sc);
        }
      }
  }
}

// ---------------------------------------------------------------------------
// Flash attention v9 = v7 body (R0's best-measured) + two changes:
// (1) XCD-clustered block decode: hardware maps bid%8 -> XCD; give each XCD
//     4 fixed (b,h) groups (K+V working set 4MB = one XCD L2) so the 16
//     qt-blocks of a head re-read K/V from L2 (34.5 TB/s) instead of L3.
//     qt-pairing for CU balance kept via dispatch rounds: round 1 (bids
//     0..255) qt=0..7, round 2 qt=15..8 land on the same CUs -> each CU
//     still totals 17 tile-pairs.
// (2) s_setprio(1/0) around MFMA pairs (T5: attn has wave role-diversity,
//     the regime where setprio measured +4-7%; NULL only on lockstep GEMM).
// Body otherwise identical to v7: register-resident P + 4-slot LDS rotation,
// one barrier per PAIR of 64-key tiles, 64KB LDS, 512 thr, 128-row q-tile,
// 8 waves x 16 q-rows; pi-permuted V -> PV B-frag is one b128; fixed-max
// exp2 softmax (Q pre-scaled by 0.125*log2e in the QKV GEMM).
// ---------------------------------------------------------------------------
__global__ __launch_bounds__(512, 4) void attn_fwd(
    const bf16* __restrict__ Q, const bf16* __restrict__ K,
    const bf16* __restrict__ Vt, bf16* __restrict__ O) {
  const int bid = blockIdx.x;
  const int xcd = bid & 7;        // hardware: bid%8 -> XCD
  const int idx = bid >> 3;       // 0..63 slot within XCD
  const int rnd = idx >> 5;       // dispatch round 0/1 (first/second 256)
  const int s   = idx & 31;
  const int bh  = xcd * 4 + (s & 3);  // 4 (b,h) groups per XCD (4MB K+V = L2)
  const int x   = s >> 2;             // 0..7
  const int qt  = rnd ? (15 - x) : x; // per-CU pair sums to 15
  const int h = bh & 15, b = bh >> 4;
  const int tid = threadIdx.x;
  const int wave = tid >> 6, lane = tid & 63;
  const int quad = lane >> 4, l16 = lane & 15;

  __shared__ __align__(16) bf16 SMEM[32768];  // 64 KB, 4 slots x 8192
  bf16* Qs = &SMEM[16384];  // Q overlays slot 2

  const size_t base = ((size_t)b * 2048) * 1024 + (size_t)h * 64;
  const bf16* Qb = Q + base;
  const bf16* Kb = K + base;
  const bf16* Vtb = Vt + ((size_t)(b * 16 + h)) * 64 * 2048;
  bf16* Ob = O + base;

  const int lrow = lane >> 3;
  const int cgX = (lane & 7) ^ lrow;

#pragma unroll
  for (int c = 0; c < 2; ++c) {
    int chunk = wave * 2 + c;
    int row = chunk * 8 + lrow;
    async16(&Qb[(size_t)(qt * 128 + row) * 1024 + cgX * 8], &Qs[chunk * 512]);
  }
  {
    int row = wave * 8 + lrow;
    async16(&Kb[(size_t)row * 1024 + cgX * 8], &SMEM[0 * 8192 + wave * 512]);
    async16(&Vtb[(size_t)row * 2048 + cgX * 8],
            &SMEM[0 * 8192 + 4096 + wave * 512]);
    async16(&Kb[(size_t)(64 + row) * 1024 + cgX * 8],
            &SMEM[1 * 8192 + wave * 512]);
    async16(&Vtb[(size_t)row * 2048 + 64 + cgX * 8],
            &SMEM[1 * 8192 + 4096 + wave * 512]);
  }
  __syncthreads();

  bf16x8 aq[2];
#pragma unroll
  for (int ks = 0; ks < 2; ++ks) {
    int row = wave * 16 + l16;
    aq[ks] = *(const bf16x8*)&Qs[row * 64 + (((ks * 4 + quad) ^ (l16 & 7)) * 8)];
  }
  __syncthreads();  // Q-frag reads done before slot 2 is overwritten

  const float NEG_INF = -__builtin_inff();
  f32x4 lsv = (f32x4){0.f, 0.f, 0.f, 0.f};
  f32x4 Oacc[4];
#pragma unroll
  for (int nt = 0; nt < 4; ++nt) Oacc[nt] = (f32x4){0.f, 0.f, 0.f, 0.f};

  const int kt_end = 2 * qt + 1;           // tile count 2qt+2 (even)
  const int ktd = 2 * qt + (wave >> 2);    // this wave's diagonal tile

  for (int ktp = 0; ktp <= kt_end; ktp += 2) {
    {
      int row = wave * 8 + lrow;
      if (ktp + 2 <= kt_end) {
        int s2 = (ktp + 2) & 3;
        async16(&Kb[(size_t)((ktp + 2) * 64 + row) * 1024 + cgX * 8],
                &SMEM[s2 * 8192 + wave * 512]);
        async16(&Vtb[(size_t)row * 2048 + (ktp + 2) * 64 + cgX * 8],
                &SMEM[s2 * 8192 + 4096 + wave * 512]);
      }
      if (ktp + 3 <= kt_end) {
        int s3 = (ktp + 3) & 3;
        async16(&Kb[(size_t)((ktp + 3) * 64 + row) * 1024 + cgX * 8],
                &SMEM[s3 * 8192 + wave * 512]);
        async16(&Vtb[(size_t)row * 2048 + (ktp + 3) * 64 + cgX * 8],
                &SMEM[s3 * 8192 + 4096 + wave * 512]);
      }
    }

#pragma unroll
    for (int sub = 0; sub < 2; ++sub) {
      const int kt = ktp + sub;
      const int ko = (kt & 3) * 8192;
      const int vo = ko + 4096;
      if (kt <= ktd) {
        f32x4 sv[4];
#pragma unroll
        for (int nt = 0; nt < 4; ++nt) {
          int row = nt * 16 + l16;
          bf16x8 bk0 = *(const bf16x8*)&SMEM[ko + row * 64 +
                                             ((quad ^ (l16 & 7)) * 8)];
          bf16x8 bk1 = *(const bf16x8*)&SMEM[ko + row * 64 +
                                             (((4 + quad) ^ (l16 & 7)) * 8)];
          sv[nt] = (f32x4){0.f, 0.f, 0.f, 0.f};
          __builtin_amdgcn_s_setprio(1);
          sv[nt] = MFMA16(bk0, aq[0], sv[nt]);
          sv[nt] = MFMA16(bk1, aq[1], sv[nt]);
          __builtin_amdgcn_s_setprio(0);
        }

        if (kt == ktd) {
          const int q_rel = wave * 16 + l16;
          const int cb = (kt - 2 * qt) * 64;
#pragma unroll
          for (int nt = 0; nt < 4; ++nt) {
            const int kb = cb + nt * 16 + quad * 4;
#pragma unroll
            for (int r = 0; r < 4; ++r)
              if (kb + r > q_rel) sv[nt][r] = NEG_INF;
          }
        }

#pragma unroll
        for (int nt = 0; nt < 4; ++nt) {
#pragma unroll
          for (int r = 0; r < 4; ++r) sv[nt][r] = exp2f(sv[nt][r]);
          lsv += sv[nt];
        }
        bf16x8 apf[2];
#pragma unroll
        for (int a = 0; a < 2; ++a) {
          bf16x4 c0 = __builtin_convertvector(sv[2 * a], bf16x4);
          bf16x4 c1 = __builtin_convertvector(sv[2 * a + 1], bf16x4);
#pragma unroll
          for (int i = 0; i < 4; ++i) {
            apf[a][i] = c0[i];
            apf[a][4 + i] = c1[i];
          }
        }

#pragma unroll
        for (int nt = 0; nt < 4; ++nt) {
          const int R = nt * 16 + l16;
          bf16x8 bvf0 = *(const bf16x8*)&SMEM[vo + R * 64 +
                                              (((0 + quad) ^ (l16 & 7)) * 8)];
          bf16x8 bvf1 = *(const bf16x8*)&SMEM[vo + R * 64 +
                                              (((4 + quad) ^ (l16 & 7)) * 8)];
          __builtin_amdgcn_s_setprio(1);
          Oacc[nt] = MFMA16(apf[0], bvf0, Oacc[nt]);
          Oacc[nt] = MFMA16(apf[1], bvf1, Oacc[nt]);
          __builtin_amdgcn_s_setprio(0);
        }
      }
    }

    __syncthreads();
  }

  float ls_acc = lsv[0] + lsv[1] + lsv[2] + lsv[3];
  ls_acc += __shfl_xor(ls_acc, 16, 64);
  ls_acc += __shfl_xor(ls_acc, 32, 64);
  float rl[4];
#pragma unroll
  for (int r = 0; r < 4; ++r) rl[r] = 1.f / __shfl(ls_acc, quad * 4 + r, 64);
#pragma unroll
  for (int nt = 0; nt < 4; ++nt)
#pragma unroll
    for (int r = 0; r < 4; ++r) {
      int row = qt * 128 + wave * 16 + quad * 4 + r;
      Ob[(size_t)row * 1024 + nt * 16 + l16] = (bf16)(Oacc[nt][r] * rl[r]);
    }
}

// ---------------------------------------------------------------------------
// Launch
// ---------------------------------------------------------------------------
extern "C" void kernel_launch(void* const* d_in, const int* in_sizes, int n_in,
                              void* d_out, int out_size, void* d_ws,
                              size_t ws_size, hipStream_t stream) {
  (void)in_sizes; (void)n_in; (void)out_size; (void)ws_size;
  const float* x  = (const float*)d_in[0];
  const float* Wq = (const float*)d_in[1];
  const float* Wk = (const float*)d_in[2];
  const float* Wv = (const float*)d_in[3];
  const float* Wo = (const float*)d_in[4];
  float* out = (float*)d_out;

  bf16* ws = (bf16*)d_ws;
  const size_t WELEM = 1024u * 1024u;
  const size_t TELEM = 4096u * 1024u;
  bf16* wt  = ws;               // 4 transposed weights (8 MB)
  bf16* xbf = ws + 4 * WELEM;   // x bf16 (8 MB)
  bf16* q   = xbf + TELEM;      // q (z=0), k (z=1) via cStrideZ
  bf16* k   = q + TELEM;
  bf16* vt  = k + TELEM;        // V pre-transposed + pi-permuted by QKV
  bf16* ao  = vt + TELEM;

  const float QSCALE = 0.125f * 1.44269504088896340736f;  // 1/sqrt(64)*log2e

  prep<<<dim3(16, 16, 5), 256, 0, stream>>>(Wq, Wk, Wv, Wo, x, wt, xbf);
  gemm_bt<bf16, 4><<<dim3(256, 3), 256, 0, stream>>>(
      xbf, wt, q, (int)WELEM, (int)TELEM, QSCALE, vt);
  attn_fwd<<<dim3(512), 512, 0, stream>>>(q, k, vt, ao);
  gemm_bt<float, 2><<<dim3(512, 1), 256, 0, stream>>>(
      ao, wt + 3 * WELEM, out, 0, 0, 1.0f, nullptr);
}

// Round 5
// 159.945 us; speedup vs baseline: 1.0821x; 1.0573x over previous
//
#include <hip/hip_runtime.h>
#include <hip/hip_bf16.h>

typedef __bf16 bf16;
typedef __bf16 bf16x4 __attribute__((ext_vector_type(4)));
typedef __bf16 bf16x8 __attribute__((ext_vector_type(8)));
typedef float f32x4 __attribute__((ext_vector_type(4)));

#define MFMA16(a, b, c) __builtin_amdgcn_mfma_f32_16x16x32_bf16((a), (b), (c), 0, 0, 0)

// async global->LDS, 16B per lane; LDS dest = wave-uniform base + lane*16.
__device__ __forceinline__ void async16(const void* g, void* l) {
  typedef const unsigned int __attribute__((address_space(1))) * GP;
  typedef unsigned int __attribute__((address_space(3))) * LP;
  __builtin_amdgcn_global_load_lds((GP)g, (LP)l, 16, 0, 0);
}

// ---------------------------------------------------------------------------
// prep: z<4 -> transpose+convert weight z (fp32 [1024x1024] -> bf16 Wt[n][k]);
// z==4 -> convert x fp32 -> bf16. grid (16,16,5) x 256 threads.
// ---------------------------------------------------------------------------
__global__ __launch_bounds__(256) void prep(
    const float* __restrict__ w0, const float* __restrict__ w1,
    const float* __restrict__ w2, const float* __restrict__ w3,
    const float* __restrict__ x, bf16* __restrict__ wtOut,
    bf16* __restrict__ xOut) {
  const int t = threadIdx.x;
  if (blockIdx.z == 4) {  // x conversion
    size_t base = ((size_t)(blockIdx.y * 16 + blockIdx.x)) * 16384;
#pragma unroll
    for (int p = 0; p < 16; ++p) {
      size_t i = base + (size_t)(p * 256 + t) * 4;
      f32x4 v = *(const f32x4*)&x[i];
      bf16 o[4];
#pragma unroll
      for (int j = 0; j < 4; ++j) o[j] = (bf16)v[j];
      *(ulong1*)&xOut[i] = *(ulong1*)o;
    }
    return;
  }
  __shared__ __align__(16) float tile[64][68];
  const float* src = (blockIdx.z == 0) ? w0 : (blockIdx.z == 1) ? w1
                   : (blockIdx.z == 2) ? w2 : w3;
  bf16* dst = wtOut + (size_t)blockIdx.z * (1024u * 1024u);
  const int bx = blockIdx.x, by = blockIdx.y;
#pragma unroll
  for (int p = 0; p < 4; ++p) {
    int idx = t + p * 256;
    int r = idx >> 4, c4 = idx & 15;
    *(f32x4*)&tile[r][c4 * 4] =
        *(const f32x4*)&src[(size_t)(by * 64 + r) * 1024 + bx * 64 + c4 * 4];
  }
  __syncthreads();
#pragma unroll
  for (int p = 0; p < 2; ++p) {
    int idx = t + p * 256;
    int rn = idx >> 3, c8 = idx & 7;
    bf16x8 v;
#pragma unroll
    for (int i = 0; i < 8; ++i) v[i] = (bf16)tile[c8 * 8 + i][rn];
    *(bf16x8*)&dst[(size_t)(bx * 64 + rn) * 1024 + by * 64 + c8 * 8] = v;
  }
}

// ---------------------------------------------------------------------------
// GEMM (round-13 config). C = A @ W (Bt[n][k]). 128 x (NI*32) tile, BK=32
// dbuf global_load_lds, one barrier per K-step. XCD-swizzled 1D grid.
// z==0 scaled by scaleZ0; z==2 with vtOut: fused V^T epilogue with the
// PI-PERMUTED key layout. QKV: NI=4 (grid 256/z). proj: NI=2 (grid 512).
// ---------------------------------------------------------------------------
template <typename OutT, int NI>
__global__ __launch_bounds__(256, 4) void gemm_bt(
    const bf16* __restrict__ A, const bf16* __restrict__ Bt,
    OutT* __restrict__ C, int btStrideZ, int cStrideZ, float scaleZ0,
    bf16* __restrict__ vtOut) {
  constexpr int XT = 1024 / (NI * 32);
  const int bid = blockIdx.x;
  const int rr = bid & 7, tt = bid >> 3;
  const int xb = tt % XT, yb = (tt / XT) * 8 + rr;
  const int zi = blockIdx.y;

  const int tid = threadIdx.x;
  const int wave = tid >> 6, lane = tid & 63;
  const int quad = lane >> 4, l16 = lane & 15;
  const int wm = wave >> 1, wn = wave & 1;
  const int m0 = yb * 128, n0 = xb * (NI * 32);
  const bf16* Bz = Bt + (size_t)zi * (size_t)btStrideZ;
  OutT* Cz = C + (size_t)zi * (size_t)cStrideZ;
  const float sc = (zi == 0) ? scaleZ0 : 1.0f;

  __shared__ __align__(16) bf16 lsA[2][128 * 32];
  __shared__ __align__(16) bf16 lsB[2][NI * 32 * 32];

  const int lrow = lane >> 2;
  const int cgX = (lane & 3) ^ ((lrow >> 1) & 3);
  const int fR = (l16 >> 1) & 3;

  f32x4 acc[4][NI];
#pragma unroll
  for (int i = 0; i < 4; ++i)
#pragma unroll
    for (int j = 0; j < NI; ++j) acc[i][j] = (f32x4){0.f, 0.f, 0.f, 0.f};

#pragma unroll
  for (int c = 0; c < 2; ++c) {
    int chunk = wave * 2 + c;
    int row = chunk * 16 + lrow;
    async16(&A[(size_t)(m0 + row) * 1024 + cgX * 8], &lsA[0][chunk * 512]);
  }
#pragma unroll
  for (int c = 0; c < NI / 2; ++c) {
    int chunk = wave * (NI / 2) + c;
    int row = chunk * 16 + lrow;
    async16(&Bz[(size_t)(n0 + row) * 1024 + cgX * 8], &lsB[0][chunk * 512]);
  }
  __syncthreads();

  for (int it = 0; it < 32; ++it) {
    const int cur = it & 1;
    if (it < 31) {
      int k0n = (it + 1) * 32;
#pragma unroll
      for (int c = 0; c < 2; ++c) {
        int chunk = wave * 2 + c;
        int row = chunk * 16 + lrow;
        async16(&A[(size_t)(m0 + row) * 1024 + k0n + cgX * 8],
                &lsA[cur ^ 1][chunk * 512]);
      }
#pragma unroll
      for (int c = 0; c < NI / 2; ++c) {
        int chunk = wave * (NI / 2) + c;
        int row = chunk * 16 + lrow;
        async16(&Bz[(size_t)(n0 + row) * 1024 + k0n + cgX * 8],
                &lsB[cur ^ 1][chunk * 512]);
      }
    }

    bf16x8 af[4], bfr[NI];
#pragma unroll
    for (int i = 0; i < 4; ++i) {
      int ra = wm * 64 + i * 16 + l16;
      af[i] = *(const bf16x8*)&lsA[cur][ra * 32 + ((quad ^ fR) * 8)];
    }
#pragma unroll
    for (int ni = 0; ni < NI; ++ni) {
      int rb = wn * (NI * 16) + ni * 16 + l16;
      bfr[ni] = *(const bf16x8*)&lsB[cur][rb * 32 + ((quad ^ fR) * 8)];
    }
#pragma unroll
    for (int mi = 0; mi < 4; ++mi)
#pragma unroll
      for (int ni = 0; ni < NI; ++ni)
        acc[mi][ni] = MFMA16(af[mi], bfr[ni], acc[mi][ni]);

    __syncthreads();
  }

  if (zi == 2 && vtOut != nullptr) {
    // V: transposed per head -> vt[(b*16+h)][d][sPerm], pi-permuted keys.
#pragma unroll
    for (int mi = 0; mi < 4; ++mi)
#pragma unroll
      for (int ni = 0; ni < NI; ++ni) {
        int col = n0 + wn * (NI * 16) + ni * 16 + l16;
        int hd = col >> 6, d = col & 63;
        int row = m0 + wm * 64 + mi * 16 + quad * 4;
        int b = row >> 11, s = row & 2047;
        int s32 = s & 31;
        int sp = (s & ~31) + ((s32 & 12) << 1) + ((s32 >> 4) << 2);
        bf16 o[4];
#pragma unroll
        for (int r = 0; r < 4; ++r) o[r] = (bf16)acc[mi][ni][r];
        *(ulong1*)&vtOut[((size_t)(b * 16 + hd) * 64 + d) * 2048 + sp] =
            *(ulong1*)o;
      }
  } else {
#pragma unroll
    for (int mi = 0; mi < 4; ++mi)
#pragma unroll
      for (int ni = 0; ni < NI; ++ni) {
        int col = n0 + wn * (NI * 16) + ni * 16 + l16;
#pragma unroll
        for (int r = 0; r < 4; ++r) {
          int row = m0 + wm * 64 + mi * 16 + quad * 4 + r;
          Cz[(size_t)row * 1024 + col] = (OutT)(acc[mi][ni][r] * sc);
        }
      }
  }
}

// ---------------------------------------------------------------------------
// Flash attention v10 (R5): occupancy fix. R4 counters showed the real
// bottleneck: Occupancy 23% (grid 512 x 64KB LDS = 2 blk/CU, no backfill;
// causal short blocks leave CU slots empty), MfmaUtil 15%, VALUBusy 42%,
// LDS ~50%, FETCH 12MB -> latency-bound, nothing saturated.
// v10: 64-row q-tiles, 256 thr (4 waves, same per-wave 16-row frag math),
// 1024 blocks; LDS 40KB = 2 K/V slots (32KB) + Q 8KB -> 4 blk/CU x 1024 =
// ALL blocks resident (163840B = exactly the 160KiB pool), 16 waves/CU
// sustained. 2-slot rotation, barrier per tile, prefetch distance 1
// (K/V mostly L2-resident, ~200cyc, covered by 16-MFMA+softmax compute).
// Decode: each XCD owns 4 (b,h) (2MB K+V in its L2); qt mapping pairs
// big/small so strided CU groups sum constant; big-first dispatch order.
// Diagonal: ktd = qt for all waves, cb = 0. exp2 via __builtin_amdgcn_exp2f
// (pin to one v_exp_f32; VALU was 42% busy).
// ---------------------------------------------------------------------------
__global__ __launch_bounds__(256, 4) void attn_fwd(
    const bf16* __restrict__ Q, const bf16* __restrict__ K,
    const bf16* __restrict__ Vt, bf16* __restrict__ O) {
  const int bid = blockIdx.x;
  const int xcd = bid & 7;       // hardware: bid%8 -> XCD
  const int i = bid >> 3;        // 0..127 within XCD
  const int g = i & 3;           // (b,h) group within XCD
  const int j = i >> 2;          // 0..31 q-tile slot
  const int a = j & 7, bq = j >> 3;
  // big-first, pair-balanced: {31-2a, 30-2a, 2a, 2a+1} per strided CU group
  const int qt = (bq < 2) ? (31 - 2 * a - bq) : (2 * a + (bq & 1));
  const int bh = xcd * 4 + g;
  const int h = bh & 15, b = bh >> 4;
  const int tid = threadIdx.x;
  const int wave = tid >> 6, lane = tid & 63;
  const int quad = lane >> 4, l16 = lane & 15;

  __shared__ __align__(16) bf16 SMEM[20480];  // 40KB: 2x(K8K+V8K) + Q 8K
  bf16* Qs = &SMEM[16384];

  const size_t base = ((size_t)b * 2048) * 1024 + (size_t)h * 64;
  const bf16* Qb = Q + base;
  const bf16* Kb = K + base;
  const bf16* Vtb = Vt + ((size_t)(b * 16 + h)) * 64 * 2048;
  bf16* Ob = O + base;

  const int lrow = lane >> 3;
  const int cgX = (lane & 7) ^ lrow;

  // prologue: stage Q (8KB) + tile 0 (16KB)
#pragma unroll
  for (int c = 0; c < 2; ++c) {
    int chunk = wave * 2 + c;
    int row = chunk * 8 + lrow;
    async16(&Qb[(size_t)(qt * 64 + row) * 1024 + cgX * 8], &Qs[chunk * 512]);
    async16(&Kb[(size_t)row * 1024 + cgX * 8], &SMEM[chunk * 512]);
    async16(&Vtb[(size_t)row * 2048 + cgX * 8], &SMEM[4096 + chunk * 512]);
  }
  __syncthreads();

  bf16x8 aq[2];
#pragma unroll
  for (int ks = 0; ks < 2; ++ks) {
    int row = wave * 16 + l16;
    aq[ks] = *(const bf16x8*)&Qs[row * 64 + (((ks * 4 + quad) ^ (l16 & 7)) * 8)];
  }

  const float NEG_INF = -__builtin_inff();
  f32x4 lsv = (f32x4){0.f, 0.f, 0.f, 0.f};
  f32x4 Oacc[4];
#pragma unroll
  for (int nt = 0; nt < 4; ++nt) Oacc[nt] = (f32x4){0.f, 0.f, 0.f, 0.f};

  for (int kt = 0; kt <= qt; ++kt) {
    const int cur = kt & 1;
    if (kt < qt) {  // prefetch tile kt+1 into the other slot
      const int ns = (cur ^ 1) * 8192;
#pragma unroll
      for (int c = 0; c < 2; ++c) {
        int chunk = wave * 2 + c;
        int row = chunk * 8 + lrow;
        async16(&Kb[(size_t)((kt + 1) * 64 + row) * 1024 + cgX * 8],
                &SMEM[ns + chunk * 512]);
        async16(&Vtb[(size_t)row * 2048 + (kt + 1) * 64 + cgX * 8],
                &SMEM[ns + 4096 + chunk * 512]);
      }
    }

    const int ko = cur * 8192;
    const int vo = ko + 4096;

    f32x4 sv[4];
#pragma unroll
    for (int nt = 0; nt < 4; ++nt) {
      int row = nt * 16 + l16;
      bf16x8 bk0 =
          *(const bf16x8*)&SMEM[ko + row * 64 + ((quad ^ (l16 & 7)) * 8)];
      bf16x8 bk1 =
          *(const bf16x8*)&SMEM[ko + row * 64 + (((4 + quad) ^ (l16 & 7)) * 8)];
      sv[nt] = (f32x4){0.f, 0.f, 0.f, 0.f};
      __builtin_amdgcn_s_setprio(1);
      sv[nt] = MFMA16(bk0, aq[0], sv[nt]);
      sv[nt] = MFMA16(bk1, aq[1], sv[nt]);
      __builtin_amdgcn_s_setprio(0);
    }

    if (kt == qt) {  // diagonal tile: mask keys > own q-row
      const int q_rel = wave * 16 + l16;
#pragma unroll
      for (int nt = 0; nt < 4; ++nt) {
        const int kb = nt * 16 + quad * 4;
#pragma unroll
        for (int r = 0; r < 4; ++r)
          if (kb + r > q_rel) sv[nt][r] = NEG_INF;
      }
    }

#pragma unroll
    for (int nt = 0; nt < 4; ++nt) {
#pragma unroll
      for (int r = 0; r < 4; ++r) sv[nt][r] = __builtin_amdgcn_exp2f(sv[nt][r]);
      lsv += sv[nt];
    }
    bf16x8 apf[2];
#pragma unroll
    for (int a2 = 0; a2 < 2; ++a2) {
      bf16x4 c0 = __builtin_convertvector(sv[2 * a2], bf16x4);
      bf16x4 c1 = __builtin_convertvector(sv[2 * a2 + 1], bf16x4);
#pragma unroll
      for (int i2 = 0; i2 < 4; ++i2) {
        apf[a2][i2] = c0[i2];
        apf[a2][4 + i2] = c1[i2];
      }
    }

#pragma unroll
    for (int nt = 0; nt < 4; ++nt) {
      const int R = nt * 16 + l16;
      bf16x8 bvf0 =
          *(const bf16x8*)&SMEM[vo + R * 64 + ((quad ^ (l16 & 7)) * 8)];
      bf16x8 bvf1 =
          *(const bf16x8*)&SMEM[vo + R * 64 + (((4 + quad) ^ (l16 & 7)) * 8)];
      __builtin_amdgcn_s_setprio(1);
      Oacc[nt] = MFMA16(apf[0], bvf0, Oacc[nt]);
      Oacc[nt] = MFMA16(apf[1], bvf1, Oacc[nt]);
      __builtin_amdgcn_s_setprio(0);
    }

    __syncthreads();  // tile kt reads done + tile kt+1 landed (vmcnt drain)
  }

  float ls_acc = lsv[0] + lsv[1] + lsv[2] + lsv[3];
  ls_acc += __shfl_xor(ls_acc, 16, 64);
  ls_acc += __shfl_xor(ls_acc, 32, 64);
  float rl[4];
#pragma unroll
  for (int r = 0; r < 4; ++r) rl[r] = 1.f / __shfl(ls_acc, quad * 4 + r, 64);
#pragma unroll
  for (int nt = 0; nt < 4; ++nt)
#pragma unroll
    for (int r = 0; r < 4; ++r) {
      int row = qt * 64 + wave * 16 + quad * 4 + r;
      Ob[(size_t)row * 1024 + nt * 16 + l16] = (bf16)(Oacc[nt][r] * rl[r]);
    }
}

// ---------------------------------------------------------------------------
// Launch
// ---------------------------------------------------------------------------
extern "C" void kernel_launch(void* const* d_in, const int* in_sizes, int n_in,
                              void* d_out, int out_size, void* d_ws,
                              size_t ws_size, hipStream_t stream) {
  (void)in_sizes; (void)n_in; (void)out_size; (void)ws_size;
  const float* x  = (const float*)d_in[0];
  const float* Wq = (const float*)d_in[1];
  const float* Wk = (const float*)d_in[2];
  const float* Wv = (const float*)d_in[3];
  const float* Wo = (const float*)d_in[4];
  float* out = (float*)d_out;

  bf16* ws = (bf16*)d_ws;
  const size_t WELEM = 1024u * 1024u;
  const size_t TELEM = 4096u * 1024u;
  bf16* wt  = ws;               // 4 transposed weights (8 MB)
  bf16* xbf = ws + 4 * WELEM;   // x bf16 (8 MB)
  bf16* q   = xbf + TELEM;      // q (z=0), k (z=1) via cStrideZ
  bf16* k   = q + TELEM;
  bf16* vt  = k + TELEM;        // V pre-transposed + pi-permuted by QKV
  bf16* ao  = vt + TELEM;

  const float QSCALE = 0.125f * 1.44269504088896340736f;  // 1/sqrt(64)*log2e

  prep<<<dim3(16, 16, 5), 256, 0, stream>>>(Wq, Wk, Wv, Wo, x, wt, xbf);
  gemm_bt<bf16, 4><<<dim3(256, 3), 256, 0, stream>>>(
      xbf, wt, q, (int)WELEM, (int)TELEM, QSCALE, vt);
  attn_fwd<<<dim3(1024), 256, 0, stream>>>(q, k, vt, ao);
  gemm_bt<float, 2><<<dim3(512, 1), 256, 0, stream>>>(
      ao, wt + 3 * WELEM, out, 0, 0, 1.0f, nullptr);
}